// Round 2
// baseline (83467.267 us; speedup 1.0000x reference)
//
#include <hip/hip_runtime.h>
#include <hip/hip_bf16.h>

#define NEGV (-1e30f)

constexpr int B_    = 32;
constexpr int T_    = 500;
constexpr int D_    = 3072;
constexpr int S_DEN = 4000;
constexpr int E_DEN = 120000;
constexpr int S_NUM = 200;
constexpr int E_NUM = 600;
constexpr int NT    = 1024;   // threads per chain block
constexpr int NWAVE = NT / 64;

// Native LDS fp32 atomic (ds_add_f32) — plain atomicAdd emits a CAS retry
// loop for fp32 LDS on hipcc, which retry-storms under contention (R1: 3400
// cyc/edge, VALUBusy 0.5%).
__device__ __forceinline__ void lds_fadd(float* p, float v) {
    unsafeAtomicAdd(p, v);
}

// ---- pack edges into int4 {src, dst, pdf, logw-bits} ----------------------
__global__ void pack_edges(const int* __restrict__ src, const int* __restrict__ dst,
                           const int* __restrict__ pdf, const float* __restrict__ logw,
                           int4* __restrict__ out, int n) {
    int i = blockIdx.x * blockDim.x + threadIdx.x;
    if (i < n) out[i] = make_int4(src[i], dst[i], pdf[i], __float_as_int(logw[i]));
}

// ---- one block per chain: blocks [0,32) = den, [32,64) = num --------------
template<bool PACKED>
__global__ __launch_bounds__(NT)
void chain_forward(const float* __restrict__ x, const int* __restrict__ x_lengths,
                   const int* __restrict__ den_src, const int* __restrict__ den_dst,
                   const int* __restrict__ den_pdf, const float* __restrict__ den_logw,
                   const float* __restrict__ den_init, const float* __restrict__ den_final,
                   const int* __restrict__ num_src, const int* __restrict__ num_dst,
                   const int* __restrict__ num_pdf, const float* __restrict__ num_logw,
                   const float* __restrict__ num_init, const float* __restrict__ num_final,
                   const int4* __restrict__ den_pk, const int4* __restrict__ num_pk,
                   float* __restrict__ ll_out) {
    __shared__ float a_rel[S_DEN];   // alpha - running offset (max ~ 0)
    __shared__ float ssum[S_DEN];    // per-dst accumulation of exp(score)
    __shared__ float xrow[D_];       // x[b, t, :]
    __shared__ float red[NWAVE];
    __shared__ float s_m;

    const int  tid    = threadIdx.x;
    const bool is_den = blockIdx.x < B_;
    const int  b      = is_den ? blockIdx.x : blockIdx.x - B_;
    const int  S      = is_den ? S_DEN : S_NUM;
    const int  E      = is_den ? E_DEN : E_NUM;

    const int*   esrc;  const int* edst;  const int* epdf;  const float* elogw;
    const int4*  epk;
    const float* init;  const float* fin;
    if (is_den) {
        esrc = den_src; edst = den_dst; epdf = den_pdf; elogw = den_logw;
        epk  = den_pk;
        init = den_init; fin = den_final;
    } else {
        esrc = num_src + b * E_NUM; edst = num_dst + b * E_NUM;
        epdf = num_pdf + b * E_NUM; elogw = num_logw + b * E_NUM;
        epk  = num_pk + b * E_NUM;
        init = num_init + b * S_NUM; fin = num_final + b * S_NUM;
    }
    const int    len = x_lengths[b];
    const float* xb  = x + (size_t)b * T_ * D_;

    for (int s = tid; s < S; s += NT) { a_rel[s] = init[s]; ssum[s] = 0.f; }
    float off = 0.f;

    const int nfull = (E / (4 * NT)) * (4 * NT);   // unroll-4 bound

    for (int t = 0; t < len; ++t) {
        // stage x[b,t,:] (float4, coalesced)
        const float4* xr4 = reinterpret_cast<const float4*>(xb + (size_t)t * D_);
        for (int d = tid; d < D_ / 4; d += NT)
            reinterpret_cast<float4*>(xrow)[d] = xr4[d];
        __syncthreads();

        // edge pass: ssum[dst] += exp(a_rel[src] + logw + x[t,pdf])
        if (PACKED) {
            int e = tid;
            for (; e < nfull; e += 4 * NT) {
                int4 p0 = epk[e];
                int4 p1 = epk[e +     NT];
                int4 p2 = epk[e + 2 * NT];
                int4 p3 = epk[e + 3 * NT];
                float v0 = a_rel[p0.x] + __int_as_float(p0.w) + xrow[p0.z];
                float v1 = a_rel[p1.x] + __int_as_float(p1.w) + xrow[p1.z];
                float v2 = a_rel[p2.x] + __int_as_float(p2.w) + xrow[p2.z];
                float v3 = a_rel[p3.x] + __int_as_float(p3.w) + xrow[p3.z];
                lds_fadd(&ssum[p0.y], __expf(v0));
                lds_fadd(&ssum[p1.y], __expf(v1));
                lds_fadd(&ssum[p2.y], __expf(v2));
                lds_fadd(&ssum[p3.y], __expf(v3));
            }
            for (; e < E; e += NT) {
                int4 p = epk[e];
                float v = a_rel[p.x] + __int_as_float(p.w) + xrow[p.z];
                lds_fadd(&ssum[p.y], __expf(v));
            }
        } else {
            for (int e = tid; e < E; e += NT) {
                float v = a_rel[esrc[e]] + elogw[e] + xrow[epdf[e]];
                lds_fadd(&ssum[edst[e]], __expf(v));
            }
        }
        __syncthreads();

        // alpha update + renormalize: a_rel = log(ssum) - m,  off += m
        float lm = -3.0e38f;
        for (int s = tid; s < S; s += NT) {
            float v  = ssum[s];
            float nr = (v > 0.f) ? __logf(v) : NEGV;
            a_rel[s] = nr;
            lm = fmaxf(lm, nr);
        }
        #pragma unroll
        for (int o = 32; o > 0; o >>= 1) lm = fmaxf(lm, __shfl_down(lm, o));
        if ((tid & 63) == 0) red[tid >> 6] = lm;
        __syncthreads();
        if (tid == 0) {
            float m = red[0];
            #pragma unroll
            for (int w = 1; w < NWAVE; ++w) m = fmaxf(m, red[w]);
            if (m < -1e29f) m = 0.f;   // all-dead guard
            s_m = m;
        }
        __syncthreads();
        float m = s_m;
        off += m;
        for (int s = tid; s < S; s += NT) { a_rel[s] -= m; ssum[s] = 0.f; }
        // no barrier needed: next-iteration stage + barrier orders a_rel/ssum
    }

    // ll = off + log( sum_s exp(a_rel[s] + final[s]) )   (a_rel <= 0, no overflow)
    float lsum = 0.f;
    for (int s = tid; s < S; s += NT) lsum += __expf(a_rel[s] + fin[s]);
    #pragma unroll
    for (int o = 32; o > 0; o >>= 1) lsum += __shfl_down(lsum, o);
    if ((tid & 63) == 0) red[tid >> 6] = lsum;
    __syncthreads();
    if (tid == 0) {
        float tot = 0.f;
        #pragma unroll
        for (int w = 0; w < NWAVE; ++w) tot += red[w];
        ll_out[blockIdx.x] = off + __logf(tot);
    }
}

// ---- combine: objf = (sum den_ll - sum num_ll) / sum(lengths) -------------
__global__ void finalize_loss(const float* __restrict__ ll, const int* __restrict__ x_lengths,
                              float* __restrict__ out) {
    int tid = threadIdx.x;              // 64 threads, 1 block
    float d = (tid < B_) ? ll[tid] : 0.f;
    float n = (tid < B_) ? ll[B_ + tid] : 0.f;
    float l = (tid < B_) ? (float)x_lengths[tid] : 0.f;
    #pragma unroll
    for (int o = 32; o > 0; o >>= 1) {
        d += __shfl_down(d, o);
        n += __shfl_down(n, o);
        l += __shfl_down(l, o);
    }
    if (tid == 0) out[0] = (d - n) / l;
}

extern "C" void kernel_launch(void* const* d_in, const int* in_sizes, int n_in,
                              void* d_out, int out_size, void* d_ws, size_t ws_size,
                              hipStream_t stream) {
    const float* x         = (const float*)d_in[0];
    const int*   x_lengths = (const int*)  d_in[1];
    const int*   den_src   = (const int*)  d_in[2];
    const int*   den_dst   = (const int*)  d_in[3];
    const int*   den_pdf   = (const int*)  d_in[4];
    const float* den_logw  = (const float*)d_in[5];
    const float* den_init  = (const float*)d_in[6];
    const float* den_final = (const float*)d_in[7];
    const int*   num_src   = (const int*)  d_in[8];
    const int*   num_dst   = (const int*)  d_in[9];
    const int*   num_pdf   = (const int*)  d_in[10];
    const float* num_logw  = (const float*)d_in[11];
    const float* num_init  = (const float*)d_in[12];
    const float* num_final = (const float*)d_in[13];

    float* ll = (float*)d_ws;                                   // 64 floats
    int4*  den_pk = (int4*)((char*)d_ws + 256);
    int4*  num_pk = den_pk + E_DEN;
    size_t need = 256 + (size_t)(E_DEN + B_ * E_NUM) * sizeof(int4);

    if (ws_size >= need) {
        pack_edges<<<(E_DEN + 255) / 256, 256, 0, stream>>>(
            den_src, den_dst, den_pdf, den_logw, den_pk, E_DEN);
        pack_edges<<<(B_ * E_NUM + 255) / 256, 256, 0, stream>>>(
            num_src, num_dst, num_pdf, num_logw, num_pk, B_ * E_NUM);
        chain_forward<true><<<2 * B_, NT, 0, stream>>>(
            x, x_lengths, den_src, den_dst, den_pdf, den_logw, den_init, den_final,
            num_src, num_dst, num_pdf, num_logw, num_init, num_final,
            den_pk, num_pk, ll);
    } else {
        chain_forward<false><<<2 * B_, NT, 0, stream>>>(
            x, x_lengths, den_src, den_dst, den_pdf, den_logw, den_init, den_final,
            num_src, num_dst, num_pdf, num_logw, num_init, num_final,
            den_pk, num_pk, ll);
    }
    finalize_loss<<<1, 64, 0, stream>>>(ll, x_lengths, (float*)d_out);
}

// Round 3
// 83220.514 us; speedup vs baseline: 1.0030x; 1.0030x over previous
//
#include <hip/hip_runtime.h>
#include <hip/hip_bf16.h>

constexpr int B_    = 32;
constexpr int T_    = 500;
constexpr int D_    = 3072;
constexpr int S_DEN = 4000;
constexpr int E_DEN = 120000;
constexpr int S_NUM = 200;
constexpr int E_NUM = 600;
constexpr int NT    = 1024;   // threads per chain block
constexpr int NWAVE = NT / 64;

// ---- pack edges into int4 {src, dst, pdf, exp(logw)-bits} -----------------
__global__ void pack_edges(const int* __restrict__ src, const int* __restrict__ dst,
                           const int* __restrict__ pdf, const float* __restrict__ logw,
                           int4* __restrict__ out, int n) {
    int i = blockIdx.x * blockDim.x + threadIdx.x;
    if (i < n) out[i] = make_int4(src[i], dst[i], pdf[i], __float_as_int(__expf(logw[i])));
}

// ---- one block per chain: blocks [0,32) = den, [32,64) = num --------------
// Linear-domain forward: ea[s] = exp(alpha[s] - off); per step
//   ssum[dst] += ea[src] * exp(logw) * exp(x[t,pdf]);  M = max ssum;
//   ea = ssum/M; off += log M.
// exp/log only on S+D elements per step, never per edge.
template<bool PACKED>
__global__ __launch_bounds__(NT)
void chain_forward(const float* __restrict__ x, const int* __restrict__ x_lengths,
                   const int* __restrict__ den_src, const int* __restrict__ den_dst,
                   const int* __restrict__ den_pdf, const float* __restrict__ den_logw,
                   const float* __restrict__ den_init, const float* __restrict__ den_final,
                   const int* __restrict__ num_src, const int* __restrict__ num_dst,
                   const int* __restrict__ num_pdf, const float* __restrict__ num_logw,
                   const float* __restrict__ num_init, const float* __restrict__ num_final,
                   const int4* __restrict__ den_pk, const int4* __restrict__ num_pk,
                   float* __restrict__ ll_out) {
    __shared__ float ea[S_DEN];    // exp(alpha - off) in [0,1]
    __shared__ float ssum[S_DEN];  // linear-domain accumulation
    __shared__ float ex[D_];       // exp(x[b,t,:])
    __shared__ float red[NWAVE];
    __shared__ float s_m;

    const int  tid    = threadIdx.x;
    const bool is_den = blockIdx.x < B_;
    const int  b      = is_den ? blockIdx.x : blockIdx.x - B_;
    const int  S      = is_den ? S_DEN : S_NUM;
    const int  E      = is_den ? E_DEN : E_NUM;

    const int*   esrc;  const int* edst;  const int* epdf;  const float* elogw;
    const int4*  epk;
    const float* init;  const float* fin;
    if (is_den) {
        esrc = den_src; edst = den_dst; epdf = den_pdf; elogw = den_logw;
        epk  = den_pk;
        init = den_init; fin = den_final;
    } else {
        esrc = num_src + b * E_NUM; edst = num_dst + b * E_NUM;
        epdf = num_pdf + b * E_NUM; elogw = num_logw + b * E_NUM;
        epk  = num_pk + b * E_NUM;
        init = num_init + b * S_NUM; fin = num_final + b * S_NUM;
    }
    const int    len = x_lengths[b];
    const float* xb  = x + (size_t)b * T_ * D_;

    for (int s = tid; s < S; s += NT) { ea[s] = __expf(init[s]); ssum[s] = 0.f; }
    float off = 0.f;

    for (int t = 0; t < len; ++t) {
        // phase A: ex[d] = exp(x[b,t,d])  (float4, coalesced; clamp for safety)
        const float4* xr4 = reinterpret_cast<const float4*>(xb + (size_t)t * D_);
        for (int d = tid; d < D_ / 4; d += NT) {
            float4 v = xr4[d];
            ex[4 * d + 0] = __expf(fminf(v.x, 60.f));
            ex[4 * d + 1] = __expf(fminf(v.y, 60.f));
            ex[4 * d + 2] = __expf(fminf(v.z, 60.f));
            ex[4 * d + 3] = __expf(fminf(v.w, 60.f));
        }
        __syncthreads();   // ex ready; also orders prev-step ea/ssum writes

        // phase B: edge pass, 8-deep batched for memory-level parallelism
        if (PACKED) {
            int e = tid;
            for (; e + 7 * NT < E; e += 8 * NT) {
                int4 p[8];
                #pragma unroll
                for (int k = 0; k < 8; ++k) p[k] = epk[e + k * NT];
                float va[8], vx[8];
                #pragma unroll
                for (int k = 0; k < 8; ++k) { va[k] = ea[p[k].x]; vx[k] = ex[p[k].z]; }
                #pragma unroll
                for (int k = 0; k < 8; ++k)
                    unsafeAtomicAdd(&ssum[p[k].y], va[k] * __int_as_float(p[k].w) * vx[k]);
            }
            for (; e < E; e += NT) {
                int4 p = epk[e];
                unsafeAtomicAdd(&ssum[p.y], ea[p.x] * __int_as_float(p.w) * ex[p.z]);
            }
        } else {
            int e = tid;
            for (; e + 3 * NT < E; e += 4 * NT) {
                int   s0 = esrc[e], s1 = esrc[e + NT], s2 = esrc[e + 2 * NT], s3 = esrc[e + 3 * NT];
                int   d0 = edst[e], d1 = edst[e + NT], d2 = edst[e + 2 * NT], d3 = edst[e + 3 * NT];
                int   p0 = epdf[e], p1 = epdf[e + NT], p2 = epdf[e + 2 * NT], p3 = epdf[e + 3 * NT];
                float w0 = elogw[e], w1 = elogw[e + NT], w2 = elogw[e + 2 * NT], w3 = elogw[e + 3 * NT];
                unsafeAtomicAdd(&ssum[d0], ea[s0] * __expf(w0) * ex[p0]);
                unsafeAtomicAdd(&ssum[d1], ea[s1] * __expf(w1) * ex[p1]);
                unsafeAtomicAdd(&ssum[d2], ea[s2] * __expf(w2) * ex[p2]);
                unsafeAtomicAdd(&ssum[d3], ea[s3] * __expf(w3) * ex[p3]);
            }
            for (; e < E; e += NT) {
                unsafeAtomicAdd(&ssum[edst[e]], ea[esrc[e]] * __expf(elogw[e]) * ex[epdf[e]]);
            }
        }
        __syncthreads();

        // phase C: M = max(ssum); renorm ea = ssum/M; off += log M; zero ssum
        float lm = 0.f;
        for (int s = tid; s < S; s += NT) lm = fmaxf(lm, ssum[s]);
        #pragma unroll
        for (int o = 32; o > 0; o >>= 1) lm = fmaxf(lm, __shfl_down(lm, o));
        if ((tid & 63) == 0) red[tid >> 6] = lm;
        __syncthreads();
        if (tid == 0) {
            float m = red[0];
            #pragma unroll
            for (int w = 1; w < NWAVE; ++w) m = fmaxf(m, red[w]);
            s_m = (m > 0.f) ? m : 1.f;
        }
        __syncthreads();
        float M   = s_m;
        float inv = 1.0f / M;
        off += __logf(M);
        for (int s = tid; s < S; s += NT) { ea[s] = ssum[s] * inv; ssum[s] = 0.f; }
        // next iteration's first barrier orders these writes
    }

    // ll = off + log( sum_s ea[s] * exp(final[s]) )
    float lsum = 0.f;
    for (int s = tid; s < S; s += NT) lsum += ea[s] * __expf(fin[s]);
    #pragma unroll
    for (int o = 32; o > 0; o >>= 1) lsum += __shfl_down(lsum, o);
    if ((tid & 63) == 0) red[tid >> 6] = lsum;
    __syncthreads();
    if (tid == 0) {
        float tot = 0.f;
        #pragma unroll
        for (int w = 0; w < NWAVE; ++w) tot += red[w];
        ll_out[blockIdx.x] = off + __logf(tot);
    }
}

// ---- combine: objf = (sum den_ll - sum num_ll) / sum(lengths) -------------
__global__ void finalize_loss(const float* __restrict__ ll, const int* __restrict__ x_lengths,
                              float* __restrict__ out) {
    int tid = threadIdx.x;              // 64 threads, 1 block
    float d = (tid < B_) ? ll[tid] : 0.f;
    float n = (tid < B_) ? ll[B_ + tid] : 0.f;
    float l = (tid < B_) ? (float)x_lengths[tid] : 0.f;
    #pragma unroll
    for (int o = 32; o > 0; o >>= 1) {
        d += __shfl_down(d, o);
        n += __shfl_down(n, o);
        l += __shfl_down(l, o);
    }
    if (tid == 0) out[0] = (d - n) / l;
}

extern "C" void kernel_launch(void* const* d_in, const int* in_sizes, int n_in,
                              void* d_out, int out_size, void* d_ws, size_t ws_size,
                              hipStream_t stream) {
    const float* x         = (const float*)d_in[0];
    const int*   x_lengths = (const int*)  d_in[1];
    const int*   den_src   = (const int*)  d_in[2];
    const int*   den_dst   = (const int*)  d_in[3];
    const int*   den_pdf   = (const int*)  d_in[4];
    const float* den_logw  = (const float*)d_in[5];
    const float* den_init  = (const float*)d_in[6];
    const float* den_final = (const float*)d_in[7];
    const int*   num_src   = (const int*)  d_in[8];
    const int*   num_dst   = (const int*)  d_in[9];
    const int*   num_pdf   = (const int*)  d_in[10];
    const float* num_logw  = (const float*)d_in[11];
    const float* num_init  = (const float*)d_in[12];
    const float* num_final = (const float*)d_in[13];

    float* ll = (float*)d_ws;                                   // 64 floats
    int4*  den_pk = (int4*)((char*)d_ws + 256);
    int4*  num_pk = den_pk + E_DEN;
    size_t need = 256 + (size_t)(E_DEN + B_ * E_NUM) * sizeof(int4);

    if (ws_size >= need) {
        pack_edges<<<(E_DEN + 255) / 256, 256, 0, stream>>>(
            den_src, den_dst, den_pdf, den_logw, den_pk, E_DEN);
        pack_edges<<<(B_ * E_NUM + 255) / 256, 256, 0, stream>>>(
            num_src, num_dst, num_pdf, num_logw, num_pk, B_ * E_NUM);
        chain_forward<true><<<2 * B_, NT, 0, stream>>>(
            x, x_lengths, den_src, den_dst, den_pdf, den_logw, den_init, den_final,
            num_src, num_dst, num_pdf, num_logw, num_init, num_final,
            den_pk, num_pk, ll);
    } else {
        chain_forward<false><<<2 * B_, NT, 0, stream>>>(
            x, x_lengths, den_src, den_dst, den_pdf, den_logw, den_init, den_final,
            num_src, num_dst, num_pdf, num_logw, num_init, num_final,
            den_pk, num_pk, ll);
    }
    finalize_loss<<<1, 64, 0, stream>>>(ll, x_lengths, (float*)d_out);
}

// Round 4
// 10241.035 us; speedup vs baseline: 8.1503x; 8.1262x over previous
//
#include <hip/hip_runtime.h>

constexpr int B_    = 32;
constexpr int T_    = 500;
constexpr int D_    = 3072;
constexpr int S_DEN = 4000;
constexpr int E_DEN = 120000;
constexpr int S_NUM = 200;
constexpr int E_NUM = 600;
constexpr int NT    = 1024;      // threads per chain block
constexpr int NWAVE = NT / 64;
constexpr int KMAX  = 4;         // states per thread (KMAX*NT >= S_DEN)

// ============================ CSR build =====================================
__global__ void zero_ints(int* p, int n) {
    int i = blockIdx.x * 256 + threadIdx.x;
    if (i < n) p[i] = 0;
}

__global__ void hist_den(const int* __restrict__ dst, int* __restrict__ cnt) {
    int e = blockIdx.x * 256 + threadIdx.x;
    if (e < E_DEN) atomicAdd(&cnt[dst[e]], 1);
}

__global__ void hist_num(const int* __restrict__ dst, int* __restrict__ cnt) { // grid (3,32)
    int b = blockIdx.y, j = blockIdx.x * 256 + threadIdx.x;
    if (j < E_NUM) atomicAdd(&cnt[b * S_NUM + dst[b * E_NUM + j]], 1);
}

__global__ void scan_den(int* __restrict__ cnt_cur, int* __restrict__ row) { // 1 block, 1024 thr
    __shared__ int part[1024];
    int tid = threadIdx.x, base = tid * 4;
    int c[4], pre[4], s = 0;
    #pragma unroll
    for (int j = 0; j < 4; ++j) {
        int idx = base + j;
        c[j] = (idx < S_DEN) ? cnt_cur[idx] : 0;
        pre[j] = s; s += c[j];
    }
    part[tid] = s; __syncthreads();
    for (int off = 1; off < 1024; off <<= 1) {
        int v = (tid >= off) ? part[tid - off] : 0; __syncthreads();
        part[tid] += v; __syncthreads();
    }
    int offs = (tid > 0) ? part[tid - 1] : 0;
    #pragma unroll
    for (int j = 0; j < 4; ++j) {
        int idx = base + j;
        if (idx < S_DEN) { row[idx] = offs + pre[j]; cnt_cur[idx] = offs + pre[j]; }
    }
    if (tid == 1023) row[S_DEN] = part[1023];
}

__global__ void scan_num(int* __restrict__ cnt_cur, int* __restrict__ row) { // 32 blocks × 256
    __shared__ int part[256];
    int b = blockIdx.x, tid = threadIdx.x;
    int c = (tid < S_NUM) ? cnt_cur[b * S_NUM + tid] : 0;
    part[tid] = c; __syncthreads();
    for (int off = 1; off < 256; off <<= 1) {
        int v = (tid >= off) ? part[tid - off] : 0; __syncthreads();
        part[tid] += v; __syncthreads();
    }
    int excl = part[tid] - c;
    if (tid < S_NUM) { row[b * (S_NUM + 1) + tid] = excl; cnt_cur[b * S_NUM + tid] = excl; }
    if (tid == 255) row[b * (S_NUM + 1) + S_NUM] = part[255];
}

// edge payload: {src | pdf<<12, float_bits(exp(logw))} — 8 B/edge
__global__ void scatter_den(const int* __restrict__ src, const int* __restrict__ dst,
                            const int* __restrict__ pdf, const float* __restrict__ logw,
                            int* __restrict__ cur, int2* __restrict__ csr) {
    int e = blockIdx.x * 256 + threadIdx.x;
    if (e >= E_DEN) return;
    int pos = atomicAdd(&cur[dst[e]], 1);
    csr[pos] = make_int2(src[e] | (pdf[e] << 12), __float_as_int(__expf(logw[e])));
}

__global__ void scatter_num(const int* __restrict__ src, const int* __restrict__ dst,
                            const int* __restrict__ pdf, const float* __restrict__ logw,
                            int* __restrict__ cur, int2* __restrict__ csr) { // grid (3,32)
    int b = blockIdx.y, j = blockIdx.x * 256 + threadIdx.x;
    if (j >= E_NUM) return;
    int e = b * E_NUM + j;
    int pos = atomicAdd(&cur[b * S_NUM + dst[e]], 1);
    csr[b * E_NUM + pos] = make_int2(src[e] | (pdf[e] << 12), __float_as_int(__expf(logw[e])));
}

// ===================== forward recursion (CSR gather) =======================
// Linear domain: ea[s] = exp(alpha[s] - off) in [0,1].
// Per step: acc[s] = sum_{in-edges} ea[src]*exp(logw)*exp(x[t,pdf]) in REGISTERS
// (thread owns states tid + k*NT) -> M = max acc (LDS ds_max_u32) ->
// ea[s] = acc/M, off += log M. No LDS atomics, no ssum array.
__global__ __launch_bounds__(NT, 4)
void chain_forward_csr(const float* __restrict__ x, const int* __restrict__ x_lengths,
                       const int* __restrict__ den_row, const int2* __restrict__ den_csr,
                       const float* __restrict__ den_init, const float* __restrict__ den_final,
                       const int* __restrict__ num_row, const int2* __restrict__ num_csr,
                       const float* __restrict__ num_init, const float* __restrict__ num_final,
                       float* __restrict__ ll_out) {
    __shared__ float    ea[S_DEN];
    __shared__ float    ex[D_];
    __shared__ float    red[NWAVE];
    __shared__ unsigned mslot[2];

    const int  tid    = threadIdx.x;
    const bool is_den = blockIdx.x < B_;
    const int  b      = is_den ? blockIdx.x : blockIdx.x - B_;
    const int  S      = is_den ? S_DEN : S_NUM;
    const int*   row  = is_den ? den_row  : num_row + b * (S_NUM + 1);
    const int2*  csr  = is_den ? den_csr  : num_csr + b * E_NUM;
    const float* init = is_den ? den_init : num_init + b * S_NUM;
    const float* fin  = is_den ? den_final: num_final + b * S_NUM;
    const int    len  = x_lengths[b];
    const float* xb   = x + (size_t)b * T_ * D_;

    int beg[KMAX], end[KMAX];
    #pragma unroll
    for (int k = 0; k < KMAX; ++k) {
        int sid = tid + k * NT;
        beg[k] = (sid < S) ? row[sid] : 0;
        end[k] = (sid < S) ? row[sid + 1] : 0;
    }
    for (int s = tid; s < S; s += NT) ea[s] = __expf(init[s]);
    if (tid == 0) { mslot[0] = 0u; mslot[1] = 0u; }

    float acc[KMAX] = {0.f, 0.f, 0.f, 0.f};
    float off = 0.f, last_inv = 1.f;

    for (int t = 0; t < len; ++t) {
        // phase A: ex = exp(x[b,t,:])
        const float4* xr4 = reinterpret_cast<const float4*>(xb + (size_t)t * D_);
        for (int d = tid; d < D_ / 4; d += NT) {
            float4 v = xr4[d];
            float4 ev;
            ev.x = __expf(fminf(v.x, 60.f));
            ev.y = __expf(fminf(v.y, 60.f));
            ev.z = __expf(fminf(v.z, 60.f));
            ev.w = __expf(fminf(v.w, 60.f));
            reinterpret_cast<float4*>(ex)[d] = ev;
        }
        __syncthreads();   // ex ready; also orders prev-step ea writes

        // phase B: register-gather per owned state
        float lm = 0.f;
        #pragma unroll
        for (int k = 0; k < KMAX; ++k) {
            float a0 = 0.f, a1 = 0.f;
            int e = beg[k], en = end[k];
            for (; e + 4 <= en; e += 4) {
                int2 p0 = csr[e], p1 = csr[e + 1], p2 = csr[e + 2], p3 = csr[e + 3];
                a0 += ea[p0.x & 0xFFF] * __int_as_float(p0.y) * ex[p0.x >> 12];
                a1 += ea[p1.x & 0xFFF] * __int_as_float(p1.y) * ex[p1.x >> 12];
                a0 += ea[p2.x & 0xFFF] * __int_as_float(p2.y) * ex[p2.x >> 12];
                a1 += ea[p3.x & 0xFFF] * __int_as_float(p3.y) * ex[p3.x >> 12];
            }
            for (; e < en; ++e) {
                int2 p = csr[e];
                a0 += ea[p.x & 0xFFF] * __int_as_float(p.y) * ex[p.x >> 12];
            }
            acc[k] = a0 + a1;
            lm = fmaxf(lm, acc[k]);
        }

        // phase C: M = block-max(acc) via wave shuffle + LDS atomic umax
        #pragma unroll
        for (int o = 32; o > 0; o >>= 1) lm = fmaxf(lm, __shfl_down(lm, o));
        if ((tid & 63) == 0) atomicMax(&mslot[t & 1], __float_as_uint(lm));
        if (tid == 0) mslot[(t + 1) & 1] = 0u;   // pre-zero the other slot
        __syncthreads();
        float M = __uint_as_float(mslot[t & 1]);
        if (!(M > 0.f)) M = 1.f;
        float inv = 1.f / M;
        last_inv = inv;
        off += __logf(M);
        #pragma unroll
        for (int k = 0; k < KMAX; ++k) {
            int sid = tid + k * NT;
            if (sid < S) ea[sid] = acc[k] * inv;
        }
        // next iteration's phase-A barrier orders these writes vs next reads
    }

    // ll = off + log( sum_s ea[s]*exp(final[s]) ) — ea values still in registers
    float lsum = 0.f;
    #pragma unroll
    for (int k = 0; k < KMAX; ++k) {
        int sid = tid + k * NT;
        if (sid < S) lsum += acc[k] * last_inv * __expf(fin[sid]);
    }
    #pragma unroll
    for (int o = 32; o > 0; o >>= 1) lsum += __shfl_down(lsum, o);
    if ((tid & 63) == 0) red[tid >> 6] = lsum;
    __syncthreads();
    if (tid == 0) {
        float tot = 0.f;
        #pragma unroll
        for (int w = 0; w < NWAVE; ++w) tot += red[w];
        ll_out[blockIdx.x] = off + __logf(tot);
    }
}

// ===================== fallback (no workspace): R3 scatter ==================
__global__ __launch_bounds__(NT)
void chain_forward_atomic(const float* __restrict__ x, const int* __restrict__ x_lengths,
                          const int* __restrict__ den_src, const int* __restrict__ den_dst,
                          const int* __restrict__ den_pdf, const float* __restrict__ den_logw,
                          const float* __restrict__ den_init, const float* __restrict__ den_final,
                          const int* __restrict__ num_src, const int* __restrict__ num_dst,
                          const int* __restrict__ num_pdf, const float* __restrict__ num_logw,
                          const float* __restrict__ num_init, const float* __restrict__ num_final,
                          float* __restrict__ ll_out) {
    __shared__ float ea[S_DEN];
    __shared__ float ssum[S_DEN];
    __shared__ float ex[D_];
    __shared__ float red[NWAVE];
    __shared__ float s_m;

    const int  tid    = threadIdx.x;
    const bool is_den = blockIdx.x < B_;
    const int  b      = is_den ? blockIdx.x : blockIdx.x - B_;
    const int  S      = is_den ? S_DEN : S_NUM;
    const int  E      = is_den ? E_DEN : E_NUM;
    const int*   esrc = is_den ? den_src : num_src + b * E_NUM;
    const int*   edst = is_den ? den_dst : num_dst + b * E_NUM;
    const int*   epdf = is_den ? den_pdf : num_pdf + b * E_NUM;
    const float* elw  = is_den ? den_logw: num_logw + b * E_NUM;
    const float* init = is_den ? den_init : num_init + b * S_NUM;
    const float* fin  = is_den ? den_final: num_final + b * S_NUM;
    const int    len  = x_lengths[b];
    const float* xb   = x + (size_t)b * T_ * D_;

    for (int s = tid; s < S; s += NT) { ea[s] = __expf(init[s]); ssum[s] = 0.f; }
    float off = 0.f;
    for (int t = 0; t < len; ++t) {
        const float4* xr4 = reinterpret_cast<const float4*>(xb + (size_t)t * D_);
        for (int d = tid; d < D_ / 4; d += NT) {
            float4 v = xr4[d];
            ex[4*d+0] = __expf(fminf(v.x, 60.f)); ex[4*d+1] = __expf(fminf(v.y, 60.f));
            ex[4*d+2] = __expf(fminf(v.z, 60.f)); ex[4*d+3] = __expf(fminf(v.w, 60.f));
        }
        __syncthreads();
        for (int e = tid; e < E; e += NT)
            unsafeAtomicAdd(&ssum[edst[e]], ea[esrc[e]] * __expf(elw[e]) * ex[epdf[e]]);
        __syncthreads();
        float lm = 0.f;
        for (int s = tid; s < S; s += NT) lm = fmaxf(lm, ssum[s]);
        #pragma unroll
        for (int o = 32; o > 0; o >>= 1) lm = fmaxf(lm, __shfl_down(lm, o));
        if ((tid & 63) == 0) red[tid >> 6] = lm;
        __syncthreads();
        if (tid == 0) {
            float m = red[0];
            for (int w = 1; w < NWAVE; ++w) m = fmaxf(m, red[w]);
            s_m = (m > 0.f) ? m : 1.f;
        }
        __syncthreads();
        float inv = 1.f / s_m;
        off += __logf(s_m);
        for (int s = tid; s < S; s += NT) { ea[s] = ssum[s] * inv; ssum[s] = 0.f; }
    }
    float lsum = 0.f;
    for (int s = tid; s < S; s += NT) lsum += ea[s] * __expf(fin[s]);
    #pragma unroll
    for (int o = 32; o > 0; o >>= 1) lsum += __shfl_down(lsum, o);
    if ((tid & 63) == 0) red[tid >> 6] = lsum;
    __syncthreads();
    if (tid == 0) {
        float tot = 0.f;
        for (int w = 0; w < NWAVE; ++w) tot += red[w];
        ll_out[blockIdx.x] = off + __logf(tot);
    }
}

// ===================== combine ==============================================
__global__ void finalize_loss(const float* __restrict__ ll, const int* __restrict__ x_lengths,
                              float* __restrict__ out) {
    int tid = threadIdx.x;              // 64 threads, 1 block
    float d = (tid < B_) ? ll[tid] : 0.f;
    float n = (tid < B_) ? ll[B_ + tid] : 0.f;
    float l = (tid < B_) ? (float)x_lengths[tid] : 0.f;
    #pragma unroll
    for (int o = 32; o > 0; o >>= 1) {
        d += __shfl_down(d, o); n += __shfl_down(n, o); l += __shfl_down(l, o);
    }
    if (tid == 0) out[0] = (d - n) / l;
}

static inline size_t align16(size_t v) { return (v + 15) & ~size_t(15); }

extern "C" void kernel_launch(void* const* d_in, const int* in_sizes, int n_in,
                              void* d_out, int out_size, void* d_ws, size_t ws_size,
                              hipStream_t stream) {
    const float* x         = (const float*)d_in[0];
    const int*   x_lengths = (const int*)  d_in[1];
    const int*   den_src   = (const int*)  d_in[2];
    const int*   den_dst   = (const int*)  d_in[3];
    const int*   den_pdf   = (const int*)  d_in[4];
    const float* den_logw  = (const float*)d_in[5];
    const float* den_init  = (const float*)d_in[6];
    const float* den_final = (const float*)d_in[7];
    const int*   num_src   = (const int*)  d_in[8];
    const int*   num_dst   = (const int*)  d_in[9];
    const int*   num_pdf   = (const int*)  d_in[10];
    const float* num_logw  = (const float*)d_in[11];
    const float* num_init  = (const float*)d_in[12];
    const float* num_final = (const float*)d_in[13];

    char* ws = (char*)d_ws;
    size_t o = 0;
    float* ll      = (float*)(ws + o);  o = align16(o + 64 * sizeof(float));
    int*   den_row = (int*)  (ws + o);  o = align16(o + (S_DEN + 1) * sizeof(int));
    int*   den_cur = (int*)  (ws + o);  o = align16(o + S_DEN * sizeof(int));
    int*   num_row = (int*)  (ws + o);  o = align16(o + B_ * (S_NUM + 1) * sizeof(int));
    int*   num_cur = (int*)  (ws + o);  o = align16(o + B_ * S_NUM * sizeof(int));
    int2*  den_csr = (int2*) (ws + o);  o = align16(o + (size_t)E_DEN * sizeof(int2));
    int2*  num_csr = (int2*) (ws + o);  o = align16(o + (size_t)B_ * E_NUM * sizeof(int2));
    const size_t need = o;

    if (ws_size >= need) {
        zero_ints<<<(S_DEN + 255) / 256, 256, 0, stream>>>(den_cur, S_DEN);
        zero_ints<<<(B_ * S_NUM + 255) / 256, 256, 0, stream>>>(num_cur, B_ * S_NUM);
        hist_den<<<(E_DEN + 255) / 256, 256, 0, stream>>>(den_dst, den_cur);
        hist_num<<<dim3(3, B_), 256, 0, stream>>>(num_dst, num_cur);
        scan_den<<<1, 1024, 0, stream>>>(den_cur, den_row);
        scan_num<<<B_, 256, 0, stream>>>(num_cur, num_row);
        scatter_den<<<(E_DEN + 255) / 256, 256, 0, stream>>>(
            den_src, den_dst, den_pdf, den_logw, den_cur, den_csr);
        scatter_num<<<dim3(3, B_), 256, 0, stream>>>(
            num_src, num_dst, num_pdf, num_logw, num_cur, num_csr);
        chain_forward_csr<<<2 * B_, NT, 0, stream>>>(
            x, x_lengths, den_row, den_csr, den_init, den_final,
            num_row, num_csr, num_init, num_final, ll);
    } else {
        chain_forward_atomic<<<2 * B_, NT, 0, stream>>>(
            x, x_lengths, den_src, den_dst, den_pdf, den_logw, den_init, den_final,
            num_src, num_dst, num_pdf, num_logw, num_init, num_final, ll);
    }
    finalize_loss<<<1, 64, 0, stream>>>(ll, x_lengths, (float*)d_out);
}

// Round 5
// 5883.621 us; speedup vs baseline: 14.1864x; 1.7406x over previous
//
#include <hip/hip_runtime.h>

constexpr int B_     = 32;
constexpr int T_     = 500;
constexpr int D_     = 3072;
constexpr int S_DEN  = 4000;
constexpr int E_DEN  = 120000;
constexpr int S_NUM  = 200;
constexpr int E_NUM  = 600;
constexpr int NCHUNK = 8;                 // den state chunks per utt
constexpr int CHUNK  = S_DEN / NCHUNK;    // 500
constexpr int NTS    = 256;               // threads per step block

// ============================ CSR build =====================================
__global__ void zero_ints(int* p, int n) {
    int i = blockIdx.x * 256 + threadIdx.x;
    if (i < n) p[i] = 0;
}

__global__ void hist_den(const int* __restrict__ dst, int* __restrict__ cnt) {
    int e = blockIdx.x * 256 + threadIdx.x;
    if (e < E_DEN) atomicAdd(&cnt[dst[e]], 1);
}

__global__ void hist_num(const int* __restrict__ dst, int* __restrict__ cnt) { // grid (3,32)
    int b = blockIdx.y, j = blockIdx.x * 256 + threadIdx.x;
    if (j < E_NUM) atomicAdd(&cnt[b * S_NUM + dst[b * E_NUM + j]], 1);
}

__global__ void scan_den(int* __restrict__ cnt_cur, int* __restrict__ row) { // 1 block, 1024 thr
    __shared__ int part[1024];
    int tid = threadIdx.x, base = tid * 4;
    int c[4], pre[4], s = 0;
    #pragma unroll
    for (int j = 0; j < 4; ++j) {
        int idx = base + j;
        c[j] = (idx < S_DEN) ? cnt_cur[idx] : 0;
        pre[j] = s; s += c[j];
    }
    part[tid] = s; __syncthreads();
    for (int off = 1; off < 1024; off <<= 1) {
        int v = (tid >= off) ? part[tid - off] : 0; __syncthreads();
        part[tid] += v; __syncthreads();
    }
    int offs = (tid > 0) ? part[tid - 1] : 0;
    #pragma unroll
    for (int j = 0; j < 4; ++j) {
        int idx = base + j;
        if (idx < S_DEN) { row[idx] = offs + pre[j]; cnt_cur[idx] = offs + pre[j]; }
    }
    if (tid == 1023) row[S_DEN] = part[1023];
}

__global__ void scan_num(int* __restrict__ cnt_cur, int* __restrict__ row) { // 32 blocks × 256
    __shared__ int part[256];
    int b = blockIdx.x, tid = threadIdx.x;
    int c = (tid < S_NUM) ? cnt_cur[b * S_NUM + tid] : 0;
    part[tid] = c; __syncthreads();
    for (int off = 1; off < 256; off <<= 1) {
        int v = (tid >= off) ? part[tid - off] : 0; __syncthreads();
        part[tid] += v; __syncthreads();
    }
    int excl = part[tid] - c;
    if (tid < S_NUM) { row[b * (S_NUM + 1) + tid] = excl; cnt_cur[b * S_NUM + tid] = excl; }
    if (tid == 255) row[b * (S_NUM + 1) + S_NUM] = part[255];
}

// edge payload: {src | pdf<<12, float_bits(exp(logw))} — 8 B/edge
__global__ void scatter_den(const int* __restrict__ src, const int* __restrict__ dst,
                            const int* __restrict__ pdf, const float* __restrict__ logw,
                            int* __restrict__ cur, int2* __restrict__ csr) {
    int e = blockIdx.x * 256 + threadIdx.x;
    if (e >= E_DEN) return;
    int pos = atomicAdd(&cur[dst[e]], 1);
    csr[pos] = make_int2(src[e] | (pdf[e] << 12), __float_as_int(__expf(logw[e])));
}

__global__ void scatter_num(const int* __restrict__ src, const int* __restrict__ dst,
                            const int* __restrict__ pdf, const float* __restrict__ logw,
                            int* __restrict__ cur, int2* __restrict__ csr) { // grid (3,32)
    int b = blockIdx.y, j = blockIdx.x * 256 + threadIdx.x;
    if (j >= E_NUM) return;
    int e = b * E_NUM + j;
    int pos = atomicAdd(&cur[b * S_NUM + dst[e]], 1);
    csr[b * E_NUM + pos] = make_int2(src[e] | (pdf[e] << 12), __float_as_int(__expf(logw[e])));
}

// ===================== state init ===========================================
__global__ void init_state(const float* __restrict__ den_init, const float* __restrict__ num_init,
                           float* __restrict__ EAd, float* __restrict__ EAn,
                           unsigned* __restrict__ Md, unsigned* __restrict__ Mn) {
    int b = blockIdx.x, tid = threadIdx.x;            // 32 blocks × 256
    for (int s = tid; s < S_DEN; s += 256) EAd[b * S_DEN + s] = __expf(den_init[s]);
    for (int s = tid; s < S_NUM; s += 256) EAn[b * S_NUM + s] = __expf(num_init[b * S_NUM + s]);
    for (int t = tid; t < T_; t += 256) { Md[b * T_ + t] = 0u; Mn[b * T_ + t] = 0u; }
}

// ===================== one time step ========================================
// Linear domain, lagged renorm: eal = EA_prev * (1/M[t-1]) in [0,1];
// EA_next[s] = sum_in-edges eal[src] * exp(logw) * exp(x[t,pdf]);
// M[t] = max_s EA_next (global atomicMax, finalized at the launch boundary).
// grid (B_, NCHUNK+1): y<NCHUNK = den chunk, y==NCHUNK = num (whole graph).
// b-fastest grid => all chunks of utt b land on XCD b%8 (L2 locality).
__global__ __launch_bounds__(NTS)
void step_kernel(int t, const float* __restrict__ x, const int* __restrict__ x_lengths,
                 const int* __restrict__ den_row, const int2* __restrict__ den_csr,
                 const int* __restrict__ num_row, const int2* __restrict__ num_csr,
                 float* __restrict__ EAd, float* __restrict__ EAn,
                 unsigned* __restrict__ Md, unsigned* __restrict__ Mn) {
    __shared__ float ex[D_];
    __shared__ float eal[S_DEN];

    const int b = blockIdx.x;
    const int c = blockIdx.y;
    if (t >= x_lengths[b]) return;                    // pass-through step for this utt
    const int tid = threadIdx.x;
    const bool isden = (c < NCHUNK);

    const int      S      = isden ? S_DEN : S_NUM;
    const float*   EAprev = isden ? EAd + ((size_t)(t & 1) * B_ + b) * S_DEN
                                  : EAn + ((size_t)(t & 1) * B_ + b) * S_NUM;
    float*         EAnext = isden ? EAd + ((size_t)((t + 1) & 1) * B_ + b) * S_DEN
                                  : EAn + ((size_t)((t + 1) & 1) * B_ + b) * S_NUM;
    unsigned*      Mrow   = isden ? Md + b * T_ : Mn + b * T_;
    const int*     row    = isden ? den_row : num_row + b * (S_NUM + 1);
    const int2*    csr    = isden ? den_csr : num_csr + b * E_NUM;

    float inv = 1.f;
    if (t > 0) {
        float Mv = __uint_as_float(Mrow[t - 1]);
        inv = (Mv > 0.f) ? 1.f / Mv : 1.f;
    }

    // stage ex = exp(x[b,t,:])
    const float4* xr4 = reinterpret_cast<const float4*>(x + ((size_t)b * T_ + t) * D_);
    for (int d = tid; d < D_ / 4; d += NTS) {
        float4 v = xr4[d];
        float4 ev;
        ev.x = __expf(fminf(v.x, 60.f));
        ev.y = __expf(fminf(v.y, 60.f));
        ev.z = __expf(fminf(v.z, 60.f));
        ev.w = __expf(fminf(v.w, 60.f));
        reinterpret_cast<float4*>(ex)[d] = ev;
    }
    // stage eal = EA_prev * inv (full state vector — any src may be referenced)
    for (int s = tid; s < S; s += NTS) eal[s] = EAprev[s] * inv;
    __syncthreads();

    // gather for owned states
    const int s0 = isden ? c * CHUNK : 0;
    const int s1 = isden ? s0 + CHUNK : S_NUM;
    float lmax = 0.f;
    for (int s = s0 + tid; s < s1; s += NTS) {
        float a0 = 0.f, a1 = 0.f;
        int e = row[s], en = row[s + 1];
        for (; e + 4 <= en; e += 4) {
            int2 p0 = csr[e], p1 = csr[e + 1], p2 = csr[e + 2], p3 = csr[e + 3];
            a0 += eal[p0.x & 0xFFF] * __int_as_float(p0.y) * ex[p0.x >> 12];
            a1 += eal[p1.x & 0xFFF] * __int_as_float(p1.y) * ex[p1.x >> 12];
            a0 += eal[p2.x & 0xFFF] * __int_as_float(p2.y) * ex[p2.x >> 12];
            a1 += eal[p3.x & 0xFFF] * __int_as_float(p3.y) * ex[p3.x >> 12];
        }
        for (; e < en; ++e) {
            int2 p = csr[e];
            a0 += eal[p.x & 0xFFF] * __int_as_float(p.y) * ex[p.x >> 12];
        }
        float a = a0 + a1;
        EAnext[s] = a;
        lmax = fmaxf(lmax, a);
    }
    #pragma unroll
    for (int o = 32; o > 0; o >>= 1) lmax = fmaxf(lmax, __shfl_down(lmax, o));
    if ((tid & 63) == 0) atomicMax(&Mrow[t], __float_as_uint(lmax));
}

// ===================== per-utt log-likelihood ===============================
__global__ void final_ll(const int* __restrict__ x_lengths,
                         const float* __restrict__ EAd, const float* __restrict__ EAn,
                         const unsigned* __restrict__ Md, const unsigned* __restrict__ Mn,
                         const float* __restrict__ den_final, const float* __restrict__ num_final,
                         float* __restrict__ ll) {
    __shared__ float r1[4], r2[4];
    const int k = blockIdx.x;                          // 64 blocks × 256
    const bool isden = k < B_;
    const int b = isden ? k : k - B_;
    const int len = x_lengths[b];
    const int S = isden ? S_DEN : S_NUM;
    const float* EA  = isden ? EAd + ((size_t)(len & 1) * B_ + b) * S_DEN
                             : EAn + ((size_t)(len & 1) * B_ + b) * S_NUM;
    const float* fin = isden ? den_final : num_final + b * S_NUM;
    const unsigned* Mrow = isden ? Md + b * T_ : Mn + b * T_;
    const int tid = threadIdx.x;

    float es = 0.f, ls = 0.f;
    for (int s = tid; s < S; s += 256) es += EA[s] * __expf(fin[s]);
    for (int t = tid; t < len - 1; t += 256) ls += __logf(__uint_as_float(Mrow[t]));
    #pragma unroll
    for (int o = 32; o > 0; o >>= 1) { es += __shfl_down(es, o); ls += __shfl_down(ls, o); }
    if ((tid & 63) == 0) { r1[tid >> 6] = es; r2[tid >> 6] = ls; }
    __syncthreads();
    if (tid == 0) {
        float e = 0.f, l = 0.f;
        #pragma unroll
        for (int w = 0; w < 4; ++w) { e += r1[w]; l += r2[w]; }
        ll[k] = __logf(e) + l;
    }
}

// ===================== combine ==============================================
__global__ void finalize_loss(const float* __restrict__ ll, const int* __restrict__ x_lengths,
                              float* __restrict__ out) {
    int tid = threadIdx.x;              // 64 threads, 1 block
    float d = (tid < B_) ? ll[tid] : 0.f;
    float n = (tid < B_) ? ll[B_ + tid] : 0.f;
    float l = (tid < B_) ? (float)x_lengths[tid] : 0.f;
    #pragma unroll
    for (int o = 32; o > 0; o >>= 1) {
        d += __shfl_down(d, o); n += __shfl_down(n, o); l += __shfl_down(l, o);
    }
    if (tid == 0) out[0] = (d - n) / l;
}

// ===================== fallback (no workspace) ==============================
__global__ __launch_bounds__(1024)
void chain_forward_atomic(const float* __restrict__ x, const int* __restrict__ x_lengths,
                          const int* __restrict__ den_src, const int* __restrict__ den_dst,
                          const int* __restrict__ den_pdf, const float* __restrict__ den_logw,
                          const float* __restrict__ den_init, const float* __restrict__ den_final,
                          const int* __restrict__ num_src, const int* __restrict__ num_dst,
                          const int* __restrict__ num_pdf, const float* __restrict__ num_logw,
                          const float* __restrict__ num_init, const float* __restrict__ num_final,
                          float* __restrict__ ll_out) {
    __shared__ float ea[S_DEN];
    __shared__ float ssum[S_DEN];
    __shared__ float ex[D_];
    __shared__ float red[16];
    __shared__ float s_m;
    const int  tid = threadIdx.x;
    const bool is_den = blockIdx.x < B_;
    const int  b = is_den ? blockIdx.x : blockIdx.x - B_;
    const int  S = is_den ? S_DEN : S_NUM;
    const int  E = is_den ? E_DEN : E_NUM;
    const int*   esrc = is_den ? den_src : num_src + b * E_NUM;
    const int*   edst = is_den ? den_dst : num_dst + b * E_NUM;
    const int*   epdf = is_den ? den_pdf : num_pdf + b * E_NUM;
    const float* elw  = is_den ? den_logw: num_logw + b * E_NUM;
    const float* init = is_den ? den_init : num_init + b * S_NUM;
    const float* fin  = is_den ? den_final: num_final + b * S_NUM;
    const int    len  = x_lengths[b];
    const float* xb   = x + (size_t)b * T_ * D_;
    for (int s = tid; s < S; s += 1024) { ea[s] = __expf(init[s]); ssum[s] = 0.f; }
    float off = 0.f;
    for (int t = 0; t < len; ++t) {
        const float4* xr4 = reinterpret_cast<const float4*>(xb + (size_t)t * D_);
        for (int d = tid; d < D_ / 4; d += 1024) {
            float4 v = xr4[d];
            ex[4*d+0] = __expf(fminf(v.x, 60.f)); ex[4*d+1] = __expf(fminf(v.y, 60.f));
            ex[4*d+2] = __expf(fminf(v.z, 60.f)); ex[4*d+3] = __expf(fminf(v.w, 60.f));
        }
        __syncthreads();
        for (int e = tid; e < E; e += 1024)
            unsafeAtomicAdd(&ssum[edst[e]], ea[esrc[e]] * __expf(elw[e]) * ex[epdf[e]]);
        __syncthreads();
        float lm = 0.f;
        for (int s = tid; s < S; s += 1024) lm = fmaxf(lm, ssum[s]);
        #pragma unroll
        for (int o = 32; o > 0; o >>= 1) lm = fmaxf(lm, __shfl_down(lm, o));
        if ((tid & 63) == 0) red[tid >> 6] = lm;
        __syncthreads();
        if (tid == 0) {
            float m = red[0];
            for (int w = 1; w < 16; ++w) m = fmaxf(m, red[w]);
            s_m = (m > 0.f) ? m : 1.f;
        }
        __syncthreads();
        float inv = 1.f / s_m;
        off += __logf(s_m);
        for (int s = tid; s < S; s += 1024) { ea[s] = ssum[s] * inv; ssum[s] = 0.f; }
    }
    float lsum = 0.f;
    for (int s = tid; s < S; s += 1024) lsum += ea[s] * __expf(fin[s]);
    #pragma unroll
    for (int o = 32; o > 0; o >>= 1) lsum += __shfl_down(lsum, o);
    if ((tid & 63) == 0) red[tid >> 6] = lsum;
    __syncthreads();
    if (tid == 0) {
        float tot = 0.f;
        for (int w = 0; w < 16; ++w) tot += red[w];
        ll_out[blockIdx.x] = off + __logf(tot);
    }
}

static inline size_t align16(size_t v) { return (v + 15) & ~size_t(15); }

extern "C" void kernel_launch(void* const* d_in, const int* in_sizes, int n_in,
                              void* d_out, int out_size, void* d_ws, size_t ws_size,
                              hipStream_t stream) {
    const float* x         = (const float*)d_in[0];
    const int*   x_lengths = (const int*)  d_in[1];
    const int*   den_src   = (const int*)  d_in[2];
    const int*   den_dst   = (const int*)  d_in[3];
    const int*   den_pdf   = (const int*)  d_in[4];
    const float* den_logw  = (const float*)d_in[5];
    const float* den_init  = (const float*)d_in[6];
    const float* den_final = (const float*)d_in[7];
    const int*   num_src   = (const int*)  d_in[8];
    const int*   num_dst   = (const int*)  d_in[9];
    const int*   num_pdf   = (const int*)  d_in[10];
    const float* num_logw  = (const float*)d_in[11];
    const float* num_init  = (const float*)d_in[12];
    const float* num_final = (const float*)d_in[13];

    char* ws = (char*)d_ws;
    size_t o = 0;
    float*    ll      = (float*)   (ws + o); o = align16(o + 64 * sizeof(float));
    int*      den_row = (int*)     (ws + o); o = align16(o + (S_DEN + 1) * sizeof(int));
    int*      den_cur = (int*)     (ws + o); o = align16(o + S_DEN * sizeof(int));
    int*      num_row = (int*)     (ws + o); o = align16(o + B_ * (S_NUM + 1) * sizeof(int));
    int*      num_cur = (int*)     (ws + o); o = align16(o + B_ * S_NUM * sizeof(int));
    int2*     den_csr = (int2*)    (ws + o); o = align16(o + (size_t)E_DEN * sizeof(int2));
    int2*     num_csr = (int2*)    (ws + o); o = align16(o + (size_t)B_ * E_NUM * sizeof(int2));
    float*    EAd     = (float*)   (ws + o); o = align16(o + (size_t)2 * B_ * S_DEN * sizeof(float));
    float*    EAn     = (float*)   (ws + o); o = align16(o + (size_t)2 * B_ * S_NUM * sizeof(float));
    unsigned* Md      = (unsigned*)(ws + o); o = align16(o + (size_t)B_ * T_ * sizeof(unsigned));
    unsigned* Mn      = (unsigned*)(ws + o); o = align16(o + (size_t)B_ * T_ * sizeof(unsigned));
    const size_t need = o;

    if (ws_size >= need) {
        zero_ints<<<(S_DEN + 255) / 256, 256, 0, stream>>>(den_cur, S_DEN);
        zero_ints<<<(B_ * S_NUM + 255) / 256, 256, 0, stream>>>(num_cur, B_ * S_NUM);
        hist_den<<<(E_DEN + 255) / 256, 256, 0, stream>>>(den_dst, den_cur);
        hist_num<<<dim3(3, B_), 256, 0, stream>>>(num_dst, num_cur);
        scan_den<<<1, 1024, 0, stream>>>(den_cur, den_row);
        scan_num<<<B_, 256, 0, stream>>>(num_cur, num_row);
        scatter_den<<<(E_DEN + 255) / 256, 256, 0, stream>>>(
            den_src, den_dst, den_pdf, den_logw, den_cur, den_csr);
        scatter_num<<<dim3(3, B_), 256, 0, stream>>>(
            num_src, num_dst, num_pdf, num_logw, num_cur, num_csr);
        init_state<<<B_, 256, 0, stream>>>(den_init, num_init, EAd, EAn, Md, Mn);
        for (int t = 0; t < T_; ++t) {
            step_kernel<<<dim3(B_, NCHUNK + 1), NTS, 0, stream>>>(
                t, x, x_lengths, den_row, den_csr, num_row, num_csr, EAd, EAn, Md, Mn);
        }
        final_ll<<<2 * B_, 256, 0, stream>>>(x_lengths, EAd, EAn, Md, Mn,
                                             den_final, num_final, ll);
    } else {
        chain_forward_atomic<<<2 * B_, 1024, 0, stream>>>(
            x, x_lengths, den_src, den_dst, den_pdf, den_logw, den_init, den_final,
            num_src, num_dst, num_pdf, num_logw, num_init, num_final, ll);
    }
    finalize_loss<<<1, 64, 0, stream>>>(ll, x_lengths, (float*)d_out);
}